// Round 20
// baseline (166.130 us; speedup 1.0000x reference)
//
#include <hip/hip_runtime.h>

#define T 4096
#define DM 1024
#define DK 64
#define H 16

typedef short s8 __attribute__((ext_vector_type(8)));   // 8 bf16 (4 VGPRs) MFMA frag
typedef float f4 __attribute__((ext_vector_type(4)));   // 16x16 MFMA accumulator
typedef float f16v __attribute__((ext_vector_type(16)));// 32x32 MFMA accumulator
typedef unsigned short us4 __attribute__((ext_vector_type(4)));
typedef unsigned u32x2 __attribute__((ext_vector_type(2)));
typedef unsigned u32x4 __attribute__((ext_vector_type(4)));
typedef __bf16 bf2 __attribute__((ext_vector_type(2)));

#define MFMA16(a,b,c) __builtin_amdgcn_mfma_f32_16x16x32_bf16((a),(b),(c),0,0,0)
#define MFMA32(a,b,c) __builtin_amdgcn_mfma_f32_32x32x16_bf16((a),(b),(c),0,0,0)
#define SCALE_Q 0.18033688011112042f   // 0.125 * log2(e)

__device__ __forceinline__ unsigned short f2bf(float x){
  __bf16 b = (__bf16)x;
  return __builtin_bit_cast(unsigned short, b);
}
__device__ __forceinline__ unsigned pk2(float a, float b){
  bf2 v; v[0] = (__bf16)a; v[1] = (__bf16)b; // -> v_cvt_pk_bf16_f32
  return __builtin_bit_cast(unsigned, v);
}

// async global->LDS, 16B per lane
__device__ __forceinline__ void gload16(const void* g, void* lds){
  __builtin_amdgcn_global_load_lds((const __attribute__((address_space(1))) unsigned int*)g,
                                   (__attribute__((address_space(3))) unsigned int*)lds,
                                   16, 0, 0);
}

// 32-lane-half exchange: E = [X_h0 | Y_h0], O = [X_h1 | Y_h1]
__device__ __forceinline__ void swp(unsigned X, unsigned Y, unsigned &E, unsigned &O){
#if __has_builtin(__builtin_amdgcn_permlane32_swap)
  auto a = __builtin_amdgcn_permlane32_swap(X, Y, false, false);
  E = a[0]; O = a[1];
#else
  int l = threadIdx.x & 63;
  unsigned sx = __builtin_amdgcn_ds_bpermute(((l & 31) << 2), X);
  unsigned sy = __builtin_amdgcn_ds_bpermute(((l & 31) << 2), Y);
  unsigned hx = __builtin_amdgcn_ds_bpermute((((l & 31) + 32) << 2), X);
  unsigned hy = __builtin_amdgcn_ds_bpermute((((l & 31) + 32) << 2), Y);
  E = (l < 32) ? sx : sy;
  O = (l < 32) ? hx : hy;
#endif
}

// ---- fused prep: X cvt + all weight cvts + scaled Wh cvts + bias dots ----
#define N_X   (T * DM / 4)
#define N_WOB (DM * DM / 4)
#define N_W3  (64 * DM / 4)
#define N_WH  (16 * 64 * 64 / 4)
__global__ __launch_bounds__(256) void prep_all(
    const float* __restrict__ X, const float* __restrict__ Wo,
    const float* __restrict__ Wq, const float* __restrict__ Wk, const float* __restrict__ Wv,
    const float* __restrict__ Whq, const float* __restrict__ Whk, const float* __restrict__ Whv,
    const float* __restrict__ bq, const float* __restrict__ bk, const float* __restrict__ bv,
    const float* __restrict__ bhq, const float* __restrict__ bhk, const float* __restrict__ bhv,
    unsigned short* __restrict__ Xbf, unsigned short* __restrict__ Wob,
    unsigned short* __restrict__ W3b, unsigned short* __restrict__ Whb,
    float* __restrict__ beff){
  int idx = blockIdx.x * 256 + threadIdx.x;
  if (idx < N_X){
    float4 v = reinterpret_cast<const float4*>(X)[idx];
    us4 o; o[0]=f2bf(v.x); o[1]=f2bf(v.y); o[2]=f2bf(v.z); o[3]=f2bf(v.w);
    reinterpret_cast<us4*>(Xbf)[idx] = o;
    return;
  }
  idx -= N_X;
  if (idx < N_WOB){
    float4 v = reinterpret_cast<const float4*>(Wo)[idx];
    us4 o; o[0]=f2bf(v.x); o[1]=f2bf(v.y); o[2]=f2bf(v.z); o[3]=f2bf(v.w);
    reinterpret_cast<us4*>(Wob)[idx] = o;
    return;
  }
  idx -= N_WOB;
  if (idx < 3 * N_W3){
    int seg = idx / N_W3, i = idx - seg * N_W3;
    const float* src = (seg == 0) ? Wq : ((seg == 1) ? Wk : Wv);
    float4 v = reinterpret_cast<const float4*>(src)[i];
    us4 o; o[0]=f2bf(v.x); o[1]=f2bf(v.y); o[2]=f2bf(v.z); o[3]=f2bf(v.w);
    reinterpret_cast<us4*>(W3b)[seg * N_W3 + i] = o;
    return;
  }
  idx -= 3 * N_W3;
  if (idx < 3 * N_WH){
    int seg = idx / N_WH, i = idx - seg * N_WH;
    const float* src = (seg == 0) ? Whq : ((seg == 1) ? Whk : Whv);
    float s = (seg == 0) ? SCALE_Q : 1.0f;
    float4 v = reinterpret_cast<const float4*>(src)[i];
    us4 o; o[0]=f2bf(v.x*s); o[1]=f2bf(v.y*s); o[2]=f2bf(v.z*s); o[3]=f2bf(v.w*s);
    reinterpret_cast<us4*>(Whb)[seg * N_WH + i] = o;
    return;
  }
  idx -= 3 * N_WH;
  if (idx < 3072){
    int seg = idx >> 10, j = idx & 1023;
    const float* Wh = (seg == 0) ? Whq : ((seg == 1) ? Whk : Whv);
    const float* b  = (seg == 0) ? bq  : ((seg == 1) ? bk  : bv);
    const float* bh = (seg == 0) ? bhq : ((seg == 1) ? bhk : bhv);
    float s = (seg == 0) ? SCALE_Q : 1.0f;
    const float* wr = Wh + j * 64;
    float acc = 0.f;
    #pragma unroll 8
    for (int k = 0; k < 64; ++k) acc += wr[k] * b[k];
    beff[idx] = (acc + bh[j]) * s;
  }
}

// ---- GEMM: BMxBN tile, BK=64, 4 waves (2x2), dbuf, strength-reduced ------
template<int MODE, int BM, int BN, int NT>
__global__ __launch_bounds__(256) void gemmX(const unsigned short* __restrict__ A,
                       const unsigned short* __restrict__ B,
                       const float* __restrict__ bias,
                       unsigned short* __restrict__ q_out,
                       unsigned short* __restrict__ k_out,
                       unsigned short* __restrict__ v_out,
                       float* __restrict__ f_out){
  __shared__ __align__(16) short la[2][BM * 64];
  __shared__ __align__(16) short lb[2][BN * 64];
  const int tid = threadIdx.x;
  const int wv = tid >> 6, l = tid & 63;
  const int lr = l & 15, lh = l >> 4;
  const int wr = wv >> 1, wc = wv & 1;
  const int tm = blockIdx.x / NT, tn = blockIdx.x % NT;
  const int t0 = tm * BM, o0 = tn * BN;
  constexpr int MF = BM / 32;
  constexpr int NF = BN / 32;
  constexpr int ACH = BM / 32;
  constexpr int BCH = BN / 32;
  constexpr int LAB = BM * 128;
  constexpr int LBB = BN * 128;

  f4 acc[MF][NF];
  #pragma unroll
  for (int i = 0; i < MF; ++i)
    #pragma unroll
    for (int j = 0; j < NF; ++j) acc[i][j] = (f4){0.f, 0.f, 0.f, 0.f};

  const int srow = tid >> 3;
  const int scs  = (tid & 7) ^ (srow & 7);
  const unsigned short* ap = A + (size_t)(t0 + srow) * DM + scs * 8;
  const unsigned short* bp = B + (size_t)(o0 + srow) * DM + scs * 8;
  char* ad = (char*)&la[0][0] + tid * 16;
  char* bd = (char*)&lb[0][0] + tid * 16;

  auto stage = [&](int BUF){
    #pragma unroll
    for (int i = 0; i < ACH; ++i)
      gload16(ap + (size_t)i * 32 * DM, ad + BUF * LAB + i * 4096);
    #pragma unroll
    for (int i = 0; i < BCH; ++i)
      gload16(bp + (size_t)i * 32 * DM, bd + BUF * LBB + i * 4096);
    ap += 64; bp += 64;
  };

  const int asw0 = (lh ^ (lr & 7)) * 16, asw1 = ((lh ^ 4) ^ (lr & 7)) * 16;
  const char* aB0 = (const char*)&la[0][0] + (wr * (BM / 2) + lr) * 128 + asw0;
  const char* aB1 = (const char*)&la[0][0] + (wr * (BM / 2) + lr) * 128 + asw1;
  const char* bB0 = (const char*)&lb[0][0] + (wc * (BN / 2) + lr) * 128 + asw0;
  const char* bB1 = (const char*)&lb[0][0] + (wc * (BN / 2) + lr) * 128 + asw1;

  auto step = [&](int BUF, bool dostage){
    if (dostage) stage(BUF ^ 1);
    s8 af[MF][2], bfr[NF][2];
    #pragma unroll
    for (int mf = 0; mf < MF; ++mf){
      af[mf][0] = *(const s8*)(aB0 + BUF * LAB + mf * 2048);
      af[mf][1] = *(const s8*)(aB1 + BUF * LAB + mf * 2048);
    }
    #pragma unroll
    for (int nf = 0; nf < NF; ++nf){
      bfr[nf][0] = *(const s8*)(bB0 + BUF * LBB + nf * 2048);
      bfr[nf][1] = *(const s8*)(bB1 + BUF * LBB + nf * 2048);
    }
    __builtin_amdgcn_s_setprio(1);
    #pragma unroll
    for (int mf = 0; mf < MF; ++mf)
      #pragma unroll
      for (int nf = 0; nf < NF; ++nf){
        acc[mf][nf] = MFMA16(af[mf][0], bfr[nf][0], acc[mf][nf]);
        acc[mf][nf] = MFMA16(af[mf][1], bfr[nf][1], acc[mf][nf]);
      }
    __builtin_amdgcn_s_setprio(0);
    __syncthreads();
  };

  stage(0);
  __syncthreads();
  #pragma unroll 1
  for (int t2 = 0; t2 < 8; ++t2){
    step(0, true);
    step(1, t2 < 7);
  }

  #pragma unroll
  for (int nf = 0; nf < NF; ++nf){
    int o = o0 + wc * (BN / 2) + nf * 16 + lr;
    float bs = (MODE == 4) ? 0.f : bias[o];
    int sel = o >> 6, oc = o & 63;
    unsigned short* yo = (sel == 0) ? q_out : ((sel == 1) ? k_out : v_out);
    #pragma unroll
    for (int mf = 0; mf < MF; ++mf)
      #pragma unroll
      for (int r = 0; r < 4; ++r){
        int t = t0 + wr * (BM / 2) + mf * 16 + lh * 4 + r;
        float v = acc[mf][nf][r] + bs;
        if (MODE == 2) f_out[(size_t)t * DM + o] = v;
        else           yo[(size_t)t * 64 + oc] = f2bf(v);
      }
  }
}

// ---- per-head linears v2 -------------------------------------------------
__global__ __launch_bounds__(256) void gemm_heads(const unsigned short* __restrict__ Yq,
                        const unsigned short* __restrict__ Yk,
                        const unsigned short* __restrict__ Yv,
                        const unsigned short* __restrict__ Whb,
                        const float* __restrict__ beff,
                        unsigned short* __restrict__ qhb,
                        unsigned short* __restrict__ khb,
                        unsigned short* __restrict__ vtb){
  const int tid = threadIdx.x;
  const int wv = tid >> 6, l = tid & 63;
  const int lr = l & 15, lh = l >> 4;
  const int rem = blockIdx.x % 48, tb = blockIdx.x / 48;
  const int kind = rem >> 4, h = rem & 15;
  const unsigned short* Y = (kind == 0) ? Yq : ((kind == 1) ? Yk : Yv);
  const unsigned short* B = Whb + (size_t)rem * 4096;
  const int t0 = tb * 256 + wv * 64;

  s8 wf[4][2], yf[4][2];
  #pragma unroll
  for (int nf = 0; nf < 4; ++nf)
    #pragma unroll
    for (int hf = 0; hf < 2; ++hf)
      wf[nf][hf] = *reinterpret_cast<const s8*>(B + (size_t)(nf * 16 + lr) * 64 + hf * 32 + lh * 8);
  #pragma unroll
  for (int mf = 0; mf < 4; ++mf)
    #pragma unroll
    for (int hf = 0; hf < 2; ++hf)
      yf[mf][hf] = *reinterpret_cast<const s8*>(Y + (size_t)(t0 + mf * 16 + lr) * 64 + hf * 32 + lh * 8);

  f4 acc[4][4];
  #pragma unroll
  for (int i = 0; i < 4; ++i)
    #pragma unroll
    for (int j = 0; j < 4; ++j) acc[i][j] = (f4){0.f, 0.f, 0.f, 0.f};

  if (kind < 2){
    #pragma unroll
    for (int mf = 0; mf < 4; ++mf)
      #pragma unroll
      for (int nf = 0; nf < 4; ++nf){
        acc[mf][nf] = MFMA16(yf[mf][0], wf[nf][0], acc[mf][nf]);
        acc[mf][nf] = MFMA16(yf[mf][1], wf[nf][1], acc[mf][nf]);
      }
    unsigned short* out = (kind == 0) ? qhb : khb;
    #pragma unroll
    for (int nf = 0; nf < 4; ++nf){
      int j = nf * 16 + lr;
      float bs = beff[rem * 64 + j];
      #pragma unroll
      for (int mf = 0; mf < 4; ++mf)
        #pragma unroll
        for (int r = 0; r < 4; ++r){
          int t = t0 + mf * 16 + lh * 4 + r;
          out[((size_t)h * T + t) * DK + j] = f2bf(acc[mf][nf][r] + bs);
        }
    }
  } else {
    #pragma unroll
    for (int nf = 0; nf < 4; ++nf)
      #pragma unroll
      for (int mf = 0; mf < 4; ++mf){
        acc[nf][mf] = MFMA16(wf[nf][0], yf[mf][0], acc[nf][mf]);
        acc[nf][mf] = MFMA16(wf[nf][1], yf[mf][1], acc[nf][mf]);
      }
    #pragma unroll
    for (int nf = 0; nf < 4; ++nf){
      float4 bsv = *reinterpret_cast<const float4*>(beff + rem * 64 + nf * 16 + lh * 4);
      #pragma unroll
      for (int r = 0; r < 4; ++r){
        int j = nf * 16 + lh * 4 + r;
        float bs = (r == 0) ? bsv.x : ((r == 1) ? bsv.y : ((r == 2) ? bsv.z : bsv.w));
        #pragma unroll
        for (int mf = 0; mf < 4; ++mf){
          int t = t0 + mf * 16 + lr;
          vtb[((size_t)h * DK + j) * T + t] = f2bf(acc[nf][mf][r] + bs);
        }
      }
    }
  }
}

// ---- flash attention v18: DESYNCED waves, private staging, no barriers ---
// 4 waves/block; each wave owns a private 16KB dbuf (2 x [K 4KB | V 4KB]),
// stages its own KVBLK=32 tiles, self-syncs with counted vmcnt(8). Waves
// drift out of phase -> CU scheduler fills pipe gaps across waves (T5's
// favorable regime). No __syncthreads in the whole kernel.
__global__ __launch_bounds__(256) void attn_fwd(const unsigned short* __restrict__ qh,
                         const unsigned short* __restrict__ kh,
                         const unsigned short* __restrict__ vt,
                         unsigned short* __restrict__ cat){
  __shared__ __align__(16) char ldsb[4][2][8192];   // [wave][buf][K 4KB | V 4KB]
  const int tid = threadIdx.x;
  const int wv = tid >> 6, l = tid & 63;
  const int l31 = l & 31, h5 = l >> 5, l7 = l & 7;
  const int h = blockIdx.x >> 5, qblk = blockIdx.x & 31;
  const int Q0w = qblk * 128 + wv * 32;

  // Q B-frags: col q = l31, k = kk*16 + h5*8 + j
  s8 qf[4];
  #pragma unroll
  for (int kk = 0; kk < 4; ++kk)
    qf[kk] = *reinterpret_cast<const s8*>(
        qh + ((size_t)h * T + Q0w + l31) * DK + kk * 16 + h5 * 8);

  float ls = 0.f;
  f16v oa0, oa1;
  #pragma unroll
  for (int i = 0; i < 16; ++i){ oa0[i] = 0.f; oa1[i] = 0.f; }

  // private staging (one wave stages its own 8KB tile = 8 gload16)
  // K: 32 rows x 128B; lane -> row l>>3, chunk (l&7)^(row&7)
  const int krow = l >> 3;
  const int kcs  = (l & 7) ^ (krow & 7);
  const unsigned short* kp = kh + (size_t)h * T * DK + krow * DK + kcs * 8;
  // V: 64 rows x 64B; lane -> row l>>2, chunk (l&3)^(row&3)
  const int vrow = l >> 2;
  const int vcs  = (l & 3) ^ (vrow & 3);
  const unsigned short* vp = vt + (size_t)h * DK * T + vrow * T + vcs * 8;
  char* kd = &ldsb[wv][0][0] + l * 16;        // linear dest within K 4KB
  char* vd = &ldsb[wv][0][0] + 4096 + l * 16; // linear dest within V 4KB

  auto stage = [&](int BUF){
    const int b = BUF * 8192;
    gload16(kp,            kd + b);           // K rows 0-7
    gload16(kp + 8 * DK,   kd + b + 1024);    // rows 8-15
    gload16(kp + 16 * DK,  kd + b + 2048);    // rows 16-23
    gload16(kp + 24 * DK,  kd + b + 3072);    // rows 24-31
    gload16(vp,            vd + b);           // V rows 0-15
    gload16(vp + 16 * T,   vd + b + 1024);    // rows 16-31
    gload16(vp + 32 * T,   vd + b + 2048);    // rows 32-47
    gload16(vp + 48 * T,   vd + b + 3072);    // rows 48-63
    kp += 32 * DK; vp += 32;
  };

  // persistent frag addresses (K: row l31; V: rows dt*32+l31)
  const char* kb[4];
  #pragma unroll
  for (int kk = 0; kk < 4; ++kk)
    kb[kk] = &ldsb[wv][0][0] + l31 * 128 + ((((kk << 1) | h5) ^ l7) << 4);
  const char* vb[2][2];
  #pragma unroll
  for (int dt = 0; dt < 2; ++dt)
    #pragma unroll
    for (int ks = 0; ks < 2; ++ks)
      vb[dt][ks] = &ldsb[wv][0][0] + 4096 + (dt * 32 + l31) * 64 +
                   ((((ks << 1) | h5) ^ (l31 & 3)) << 4);

  // prologue: tiles 0 and 1 in flight (16 outstanding loads)
  stage(0);
  stage(1);

  #pragma unroll 1
  for (int it = 0; it < 128; ++it){
    const int BUF = it & 1;
    // wait: tile `it` resident (allow the 8 loads of tile it+1 in flight)
    if (it < 127) asm volatile("s_waitcnt vmcnt(8)" ::: "memory");
    else          asm volatile("s_waitcnt vmcnt(0)" ::: "memory");
    __builtin_amdgcn_sched_barrier(0);

    const int bo = BUF * 8192;
    s8 kf[4], vf[2][2];
    #pragma unroll
    for (int kk = 0; kk < 4; ++kk) kf[kk] = *(const s8*)(kb[kk] + bo);
    #pragma unroll
    for (int dt = 0; dt < 2; ++dt)
      #pragma unroll
      for (int ks = 0; ks < 2; ++ks) vf[dt][ks] = *(const s8*)(vb[dt][ks] + bo);
    asm volatile("s_waitcnt lgkmcnt(0)" ::: "memory");
    __builtin_amdgcn_sched_barrier(0);
    // re-stage this buffer with tile it+2 (reads complete; no other wave touches it)
    if (it < 126) stage(BUF);

    // S^T = K·Q (32 kv x 32 q)
    f16v sc;
    #pragma unroll
    for (int i = 0; i < 16; ++i) sc[i] = 0.f;
    __builtin_amdgcn_s_setprio(1);
    #pragma unroll
    for (int kk = 0; kk < 4; ++kk) sc = MFMA32(kf[kk], qf[kk], sc);
    __builtin_amdgcn_s_setprio(0);
    // no-max softmax
    float p[16];
    #pragma unroll
    for (int i = 0; i < 16; ++i) p[i] = __builtin_amdgcn_exp2f(sc[i]);
    float r0 = (p[0]+p[1]) + (p[2]+p[3]);
    float r1 = (p[4]+p[5]) + (p[6]+p[7]);
    float r2 = (p[8]+p[9]) + (p[10]+p[11]);
    float r3 = (p[12]+p[13]) + (p[14]+p[15]);
    ls += (r0+r1) + (r2+r3);
    unsigned a0 = pk2(p[0],p[1]),  a1 = pk2(p[2],p[3]);
    unsigned a2 = pk2(p[4],p[5]),  a3 = pk2(p[6],p[7]);
    unsigned a4 = pk2(p[8],p[9]),  a5 = pk2(p[10],p[11]);
    unsigned a6 = pk2(p[12],p[13]), a7 = pk2(p[14],p[15]);
    unsigned e0,o0, e1,o1, e2,o2, e3,o3;
    swp(a0, a2, e0, o0);  swp(a1, a3, e1, o1);   // kv 0-15
    swp(a4, a6, e2, o2);  swp(a5, a7, e3, o3);   // kv 16-31
    u32x4 pu0 = {e0, e1, o0, o1};
    u32x4 pu1 = {e2, e3, o2, o3};
    s8 pa0 = __builtin_bit_cast(s8, pu0);
    s8 pa1 = __builtin_bit_cast(s8, pu1);
    // O^T += V^T · P
    __builtin_amdgcn_s_setprio(1);
    oa0 = MFMA32(vf[0][0], pa0, oa0);
    oa0 = MFMA32(vf[0][1], pa1, oa0);
    oa1 = MFMA32(vf[1][0], pa0, oa1);
    oa1 = MFMA32(vf[1][1], pa1, oa1);
    __builtin_amdgcn_s_setprio(0);
  }

  // epilogue: lane's outputs all share q = l31
  float lq = ls + __shfl_xor(ls, 32);
  float inv = 1.f / lq;
  const int t = Q0w + l31;
  unsigned short* crow = cat + (size_t)t * DM + h * DK;
  #pragma unroll
  for (int g = 0; g < 4; ++g){
    u32x2 w0, w1;
    w0[0] = pk2(oa0[g*4+0] * inv, oa0[g*4+1] * inv);
    w0[1] = pk2(oa0[g*4+2] * inv, oa0[g*4+3] * inv);
    w1[0] = pk2(oa1[g*4+0] * inv, oa1[g*4+1] * inv);
    w1[1] = pk2(oa1[g*4+2] * inv, oa1[g*4+3] * inv);
    *reinterpret_cast<u32x2*>(crow + g * 8 + h5 * 4)      = w0;
    *reinterpret_cast<u32x2*>(crow + 32 + g * 8 + h5 * 4) = w1;
  }
}

// ---------------------------------------------------------------------------
extern "C" void kernel_launch(void* const* d_in, const int* in_sizes, int n_in,
                              void* d_out, int out_size, void* d_ws, size_t ws_size,
                              hipStream_t stream){
  const float* X   = (const float*)d_in[0];
  const float* Wq  = (const float*)d_in[1];
  const float* bq  = (const float*)d_in[2];
  const float* Wk  = (const float*)d_in[3];
  const float* bk  = (const float*)d_in[4];
  const float* Wv  = (const float*)d_in[5];
  const float* bv  = (const float*)d_in[6];
  const float* Whq = (const float*)d_in[7];
  const float* bhq = (const float*)d_in[8];
  const float* Whk = (const float*)d_in[9];
  const float* bhk = (const float*)d_in[10];
  const float* Whv = (const float*)d_in[11];
  const float* bhv = (const float*)d_in[12];
  const float* Wo  = (const float*)d_in[13];
  const float* bo  = (const float*)d_in[14];

  char* w = (char*)d_ws;
  size_t off = 0;
  auto alloc = [&](size_t bytes) -> char* {
    char* p = w + off;
    off = (off + bytes + 255) & ~(size_t)255;
    return p;
  };
  unsigned short* Xbf = (unsigned short*)alloc((size_t)T * DM * 2);   // reused as cat
  unsigned short* Wob = (unsigned short*)alloc((size_t)DM * DM * 2);
  unsigned short* W3b = (unsigned short*)alloc((size_t)192 * DM * 2);
  unsigned short* Whb = (unsigned short*)alloc((size_t)48 * 64 * 64 * 2);
  float* beff = (float*)alloc(48 * 64 * 4);
  unsigned short* Yq  = (unsigned short*)alloc((size_t)T * 64 * 2);
  unsigned short* Yk  = (unsigned short*)alloc((size_t)T * 64 * 2);
  unsigned short* Yv  = (unsigned short*)alloc((size_t)T * 64 * 2);
  unsigned short* qhb = (unsigned short*)alloc((size_t)H * T * DK * 2);
  unsigned short* khb = (unsigned short*)alloc((size_t)H * T * DK * 2);
  unsigned short* vtb = (unsigned short*)alloc((size_t)H * T * DK * 2);
  unsigned short* cat = Xbf;   // alias: Xbf dead after gemm1

  {
    int total = N_X + N_WOB + 3 * N_W3 + 3 * N_WH + 3072;
    prep_all<<<(total + 255) / 256, 256, 0, stream>>>(
        X, Wo, Wq, Wk, Wv, Whq, Whk, Whv, bq, bk, bv, bhq, bhk, bhv,
        Xbf, Wob, W3b, Whb, beff);
  }

  // stage 1: Y = X · W3^T (4096 x 192 x 1024), 64x64 tiles
  gemmX<4, 64, 64, 3><<<(T / 64) * 3, 256, 0, stream>>>(Xbf, W3b, nullptr, Yq, Yk, Yv, nullptr);

  // stage 2: per-head 64x64 linears
  gemm_heads<<<(T / 256) * 48, 256, 0, stream>>>(Yq, Yk, Yv, Whb, beff, qhb, khb, vtb);

  // attention (desynced waves, private staging, no barriers)
  attn_fwd<<<(T / 128) * H, 256, 0, stream>>>(qhb, khb, vtb, cat);

  // final projection (f32 out)
  gemmX<2, 128, 64, 16><<<(T / 128) * 16, 256, 0, stream>>>(cat, Wob, bo, nullptr, nullptr, nullptr, (float*)d_out);
}

// Round 21
// 141.962 us; speedup vs baseline: 1.1702x; 1.1702x over previous
//
#include <hip/hip_runtime.h>

#define T 4096
#define DM 1024
#define DK 64
#define H 16

typedef short s8 __attribute__((ext_vector_type(8)));   // 8 bf16 (4 VGPRs) MFMA frag
typedef float f4 __attribute__((ext_vector_type(4)));   // 16x16 MFMA accumulator
typedef float f16v __attribute__((ext_vector_type(16)));// 32x32 MFMA accumulator
typedef unsigned short us4 __attribute__((ext_vector_type(4)));
typedef unsigned u32x2 __attribute__((ext_vector_type(2)));
typedef unsigned u32x4 __attribute__((ext_vector_type(4)));
typedef __bf16 bf2 __attribute__((ext_vector_type(2)));

#define MFMA16(a,b,c) __builtin_amdgcn_mfma_f32_16x16x32_bf16((a),(b),(c),0,0,0)
#define MFMA32(a,b,c) __builtin_amdgcn_mfma_f32_32x32x16_bf16((a),(b),(c),0,0,0)
#define SCALE_Q 0.18033688011112042f   // 0.125 * log2(e)

__device__ __forceinline__ unsigned short f2bf(float x){
  __bf16 b = (__bf16)x;
  return __builtin_bit_cast(unsigned short, b);
}
__device__ __forceinline__ unsigned pk2(float a, float b){
  bf2 v; v[0] = (__bf16)a; v[1] = (__bf16)b; // -> v_cvt_pk_bf16_f32
  return __builtin_bit_cast(unsigned, v);
}

// async global->LDS, 16B per lane
__device__ __forceinline__ void gload16(const void* g, void* lds){
  __builtin_amdgcn_global_load_lds((const __attribute__((address_space(1))) unsigned int*)g,
                                   (__attribute__((address_space(3))) unsigned int*)lds,
                                   16, 0, 0);
}

// 32-lane-half exchange: E = [X_h0 | Y_h0], O = [X_h1 | Y_h1]
__device__ __forceinline__ void swp(unsigned X, unsigned Y, unsigned &E, unsigned &O){
#if __has_builtin(__builtin_amdgcn_permlane32_swap)
  auto a = __builtin_amdgcn_permlane32_swap(X, Y, false, false);
  E = a[0]; O = a[1];
#else
  int l = threadIdx.x & 63;
  unsigned sx = __builtin_amdgcn_ds_bpermute(((l & 31) << 2), X);
  unsigned sy = __builtin_amdgcn_ds_bpermute(((l & 31) << 2), Y);
  unsigned hx = __builtin_amdgcn_ds_bpermute((((l & 31) + 32) << 2), X);
  unsigned hy = __builtin_amdgcn_ds_bpermute((((l & 31) + 32) << 2), Y);
  E = (l < 32) ? sx : sy;
  O = (l < 32) ? hx : hy;
#endif
}

// ---- f32 -> bf16 convert (vectorized) ------------------------------------
__global__ void cvt_bf16(const float* __restrict__ in, unsigned short* __restrict__ out, int n4){
  int i = blockIdx.x * blockDim.x + threadIdx.x;
  if (i >= n4) return;
  float4 v = reinterpret_cast<const float4*>(in)[i];
  us4 o;
  o[0] = f2bf(v.x); o[1] = f2bf(v.y); o[2] = f2bf(v.z); o[3] = f2bf(v.w);
  reinterpret_cast<us4*>(out)[i] = o;
}

// ---- fused weight prep: all cvts + scaled Wh cvts + bias dots ------------
#define N_WOB (DM * DM / 4)
#define N_W3  (64 * DM / 4)
#define N_WH  (16 * 64 * 64 / 4)
__global__ __launch_bounds__(256) void prep_all(
    const float* __restrict__ Wo,
    const float* __restrict__ Wq, const float* __restrict__ Wk, const float* __restrict__ Wv,
    const float* __restrict__ Whq, const float* __restrict__ Whk, const float* __restrict__ Whv,
    const float* __restrict__ bq, const float* __restrict__ bk, const float* __restrict__ bv,
    const float* __restrict__ bhq, const float* __restrict__ bhk, const float* __restrict__ bhv,
    unsigned short* __restrict__ Wob, unsigned short* __restrict__ W3b,
    unsigned short* __restrict__ Whb, float* __restrict__ beff){
  int idx = blockIdx.x * 256 + threadIdx.x;
  if (idx < N_WOB){
    float4 v = reinterpret_cast<const float4*>(Wo)[idx];
    us4 o; o[0]=f2bf(v.x); o[1]=f2bf(v.y); o[2]=f2bf(v.z); o[3]=f2bf(v.w);
    reinterpret_cast<us4*>(Wob)[idx] = o;
    return;
  }
  idx -= N_WOB;
  if (idx < 3 * N_W3){
    int seg = idx / N_W3, i = idx - seg * N_W3;
    const float* src = (seg == 0) ? Wq : ((seg == 1) ? Wk : Wv);
    float4 v = reinterpret_cast<const float4*>(src)[i];
    us4 o; o[0]=f2bf(v.x); o[1]=f2bf(v.y); o[2]=f2bf(v.z); o[3]=f2bf(v.w);
    reinterpret_cast<us4*>(W3b)[seg * N_W3 + i] = o;
    return;
  }
  idx -= 3 * N_W3;
  if (idx < 3 * N_WH){
    int seg = idx / N_WH, i = idx - seg * N_WH;
    const float* src = (seg == 0) ? Whq : ((seg == 1) ? Whk : Whv);
    float s = (seg == 0) ? SCALE_Q : 1.0f;
    float4 v = reinterpret_cast<const float4*>(src)[i];
    us4 o; o[0]=f2bf(v.x*s); o[1]=f2bf(v.y*s); o[2]=f2bf(v.z*s); o[3]=f2bf(v.w*s);
    reinterpret_cast<us4*>(Whb)[seg * N_WH + i] = o;
    return;
  }
  idx -= 3 * N_WH;
  if (idx < 3072){
    int seg = idx >> 10, j = idx & 1023;
    const float* Wh = (seg == 0) ? Whq : ((seg == 1) ? Whk : Whv);
    const float* b  = (seg == 0) ? bq  : ((seg == 1) ? bk  : bv);
    const float* bh = (seg == 0) ? bhq : ((seg == 1) ? bhk : bhv);
    float s = (seg == 0) ? SCALE_Q : 1.0f;
    const float* wr = Wh + j * 64;
    float acc = 0.f;
    #pragma unroll 8
    for (int k = 0; k < 64; ++k) acc += wr[k] * b[k];
    beff[idx] = (acc + bh[j]) * s;
  }
}

// ---- GEMM: BMxBN tile, BK=64, 4 waves (2x2), dbuf, strength-reduced ------
template<int MODE, int BM, int BN, int NT>
__global__ __launch_bounds__(256) void gemmX(const unsigned short* __restrict__ A,
                       const unsigned short* __restrict__ B,
                       const float* __restrict__ bias,
                       unsigned short* __restrict__ q_out,
                       unsigned short* __restrict__ k_out,
                       unsigned short* __restrict__ v_out,
                       float* __restrict__ f_out){
  __shared__ __align__(16) short la[2][BM * 64];
  __shared__ __align__(16) short lb[2][BN * 64];
  const int tid = threadIdx.x;
  const int wv = tid >> 6, l = tid & 63;
  const int lr = l & 15, lh = l >> 4;
  const int wr = wv >> 1, wc = wv & 1;
  const int tm = blockIdx.x / NT, tn = blockIdx.x % NT;
  const int t0 = tm * BM, o0 = tn * BN;
  constexpr int MF = BM / 32;
  constexpr int NF = BN / 32;
  constexpr int ACH = BM / 32;
  constexpr int BCH = BN / 32;
  constexpr int LAB = BM * 128;
  constexpr int LBB = BN * 128;

  f4 acc[MF][NF];
  #pragma unroll
  for (int i = 0; i < MF; ++i)
    #pragma unroll
    for (int j = 0; j < NF; ++j) acc[i][j] = (f4){0.f, 0.f, 0.f, 0.f};

  const int srow = tid >> 3;
  const int scs  = (tid & 7) ^ (srow & 7);
  const unsigned short* ap = A + (size_t)(t0 + srow) * DM + scs * 8;
  const unsigned short* bp = B + (size_t)(o0 + srow) * DM + scs * 8;
  char* ad = (char*)&la[0][0] + tid * 16;
  char* bd = (char*)&lb[0][0] + tid * 16;

  auto stage = [&](int BUF){
    #pragma unroll
    for (int i = 0; i < ACH; ++i)
      gload16(ap + (size_t)i * 32 * DM, ad + BUF * LAB + i * 4096);
    #pragma unroll
    for (int i = 0; i < BCH; ++i)
      gload16(bp + (size_t)i * 32 * DM, bd + BUF * LBB + i * 4096);
    ap += 64; bp += 64;
  };

  const int asw0 = (lh ^ (lr & 7)) * 16, asw1 = ((lh ^ 4) ^ (lr & 7)) * 16;
  const char* aB0 = (const char*)&la[0][0] + (wr * (BM / 2) + lr) * 128 + asw0;
  const char* aB1 = (const char*)&la[0][0] + (wr * (BM / 2) + lr) * 128 + asw1;
  const char* bB0 = (const char*)&lb[0][0] + (wc * (BN / 2) + lr) * 128 + asw0;
  const char* bB1 = (const char*)&lb[0][0] + (wc * (BN / 2) + lr) * 128 + asw1;

  auto step = [&](int BUF, bool dostage){
    if (dostage) stage(BUF ^ 1);
    s8 af[MF][2], bfr[NF][2];
    #pragma unroll
    for (int mf = 0; mf < MF; ++mf){
      af[mf][0] = *(const s8*)(aB0 + BUF * LAB + mf * 2048);
      af[mf][1] = *(const s8*)(aB1 + BUF * LAB + mf * 2048);
    }
    #pragma unroll
    for (int nf = 0; nf < NF; ++nf){
      bfr[nf][0] = *(const s8*)(bB0 + BUF * LBB + nf * 2048);
      bfr[nf][1] = *(const s8*)(bB1 + BUF * LBB + nf * 2048);
    }
    __builtin_amdgcn_s_setprio(1);
    #pragma unroll
    for (int mf = 0; mf < MF; ++mf)
      #pragma unroll
      for (int nf = 0; nf < NF; ++nf){
        acc[mf][nf] = MFMA16(af[mf][0], bfr[nf][0], acc[mf][nf]);
        acc[mf][nf] = MFMA16(af[mf][1], bfr[nf][1], acc[mf][nf]);
      }
    __builtin_amdgcn_s_setprio(0);
    __syncthreads();
  };

  stage(0);
  __syncthreads();
  #pragma unroll 1
  for (int t2 = 0; t2 < 8; ++t2){
    step(0, true);
    step(1, t2 < 7);
  }

  #pragma unroll
  for (int nf = 0; nf < NF; ++nf){
    int o = o0 + wc * (BN / 2) + nf * 16 + lr;
    float bs = (MODE == 4) ? 0.f : bias[o];
    int sel = o >> 6, oc = o & 63;
    unsigned short* yo = (sel == 0) ? q_out : ((sel == 1) ? k_out : v_out);
    #pragma unroll
    for (int mf = 0; mf < MF; ++mf)
      #pragma unroll
      for (int r = 0; r < 4; ++r){
        int t = t0 + wr * (BM / 2) + mf * 16 + lh * 4 + r;
        float v = acc[mf][nf][r] + bs;
        if (MODE == 2) f_out[(size_t)t * DM + o] = v;
        else           yo[(size_t)t * 64 + oc] = f2bf(v);
      }
  }
}

// ---- per-head linears v2 -------------------------------------------------
__global__ __launch_bounds__(256) void gemm_heads(const unsigned short* __restrict__ Yq,
                        const unsigned short* __restrict__ Yk,
                        const unsigned short* __restrict__ Yv,
                        const unsigned short* __restrict__ Whb,
                        const float* __restrict__ beff,
                        unsigned short* __restrict__ qhb,
                        unsigned short* __restrict__ khb,
                        unsigned short* __restrict__ vtb){
  const int tid = threadIdx.x;
  const int wv = tid >> 6, l = tid & 63;
  const int lr = l & 15, lh = l >> 4;
  const int rem = blockIdx.x % 48, tb = blockIdx.x / 48;
  const int kind = rem >> 4, h = rem & 15;
  const unsigned short* Y = (kind == 0) ? Yq : ((kind == 1) ? Yk : Yv);
  const unsigned short* B = Whb + (size_t)rem * 4096;
  const int t0 = tb * 256 + wv * 64;

  s8 wf[4][2], yf[4][2];
  #pragma unroll
  for (int nf = 0; nf < 4; ++nf)
    #pragma unroll
    for (int hf = 0; hf < 2; ++hf)
      wf[nf][hf] = *reinterpret_cast<const s8*>(B + (size_t)(nf * 16 + lr) * 64 + hf * 32 + lh * 8);
  #pragma unroll
  for (int mf = 0; mf < 4; ++mf)
    #pragma unroll
    for (int hf = 0; hf < 2; ++hf)
      yf[mf][hf] = *reinterpret_cast<const s8*>(Y + (size_t)(t0 + mf * 16 + lr) * 64 + hf * 32 + lh * 8);

  f4 acc[4][4];
  #pragma unroll
  for (int i = 0; i < 4; ++i)
    #pragma unroll
    for (int j = 0; j < 4; ++j) acc[i][j] = (f4){0.f, 0.f, 0.f, 0.f};

  if (kind < 2){
    #pragma unroll
    for (int mf = 0; mf < 4; ++mf)
      #pragma unroll
      for (int nf = 0; nf < 4; ++nf){
        acc[mf][nf] = MFMA16(yf[mf][0], wf[nf][0], acc[mf][nf]);
        acc[mf][nf] = MFMA16(yf[mf][1], wf[nf][1], acc[mf][nf]);
      }
    unsigned short* out = (kind == 0) ? qhb : khb;
    #pragma unroll
    for (int nf = 0; nf < 4; ++nf){
      int j = nf * 16 + lr;
      float bs = beff[rem * 64 + j];
      #pragma unroll
      for (int mf = 0; mf < 4; ++mf)
        #pragma unroll
        for (int r = 0; r < 4; ++r){
          int t = t0 + mf * 16 + lh * 4 + r;
          out[((size_t)h * T + t) * DK + j] = f2bf(acc[mf][nf][r] + bs);
        }
    }
  } else {
    #pragma unroll
    for (int nf = 0; nf < 4; ++nf)
      #pragma unroll
      for (int mf = 0; mf < 4; ++mf){
        acc[nf][mf] = MFMA16(wf[nf][0], yf[mf][0], acc[nf][mf]);
        acc[nf][mf] = MFMA16(wf[nf][1], yf[mf][1], acc[nf][mf]);
      }
    #pragma unroll
    for (int nf = 0; nf < 4; ++nf){
      float4 bsv = *reinterpret_cast<const float4*>(beff + rem * 64 + nf * 16 + lh * 4);
      #pragma unroll
      for (int r = 0; r < 4; ++r){
        int j = nf * 16 + lh * 4 + r;
        float bs = (r == 0) ? bsv.x : ((r == 1) ? bsv.y : ((r == 2) ? bsv.z : bsv.w));
        #pragma unroll
        for (int mf = 0; mf < 4; ++mf){
          int t = t0 + mf * 16 + lr;
          vtb[((size_t)h * DK + j) * T + t] = f2bf(acc[nf][mf][r] + bs);
        }
      }
    }
  }
}

// ---- flash attention v16: cross-iteration pipeline (QK(t+1) || softmax(t))
// 3 LDS buffers; sc for tile t computed in iteration t-1 -> the QK MFMA of
// t+1 overlaps the VALU softmax of t (independent pipes, chain broken).
__global__ __launch_bounds__(256) void attn_fwd(const unsigned short* __restrict__ qh,
                         const unsigned short* __restrict__ kh,
                         const unsigned short* __restrict__ vt,
                         unsigned short* __restrict__ cat){
  __shared__ __align__(16) char ldsb[3][16384];   // [BUF][ K 8KB | V 8KB ]
  const int tid = threadIdx.x;
  const int wv = tid >> 6, l = tid & 63;
  const int l31 = l & 31, h5 = l >> 5, l7 = l & 7;
  const int h = blockIdx.x >> 5, qblk = blockIdx.x & 31;
  const int Q0w = qblk * 128 + wv * 32;

  // Q B-frags: col q = l31, k = kk*16 + h5*8 + j
  s8 qf[4];
  #pragma unroll
  for (int kk = 0; kk < 4; ++kk)
    qf[kk] = *reinterpret_cast<const s8*>(
        qh + ((size_t)h * T + Q0w + l31) * DK + kk * 16 + h5 * 8);

  float ls = 0.f;
  f16v oa0, oa1;
  #pragma unroll
  for (int i = 0; i < 16; ++i){ oa0[i] = 0.f; oa1[i] = 0.f; }

  // staging (256 threads stage K 8KB + V 8KB)
  const int srow = tid >> 3;
  const int scs  = (tid & 7) ^ (srow & 7);
  const unsigned short* kp = kh + (size_t)h * T * DK + srow * DK + scs * 8;
  const unsigned short* vp = vt + (size_t)h * DK * T + srow * T + scs * 8;
  char* sd = &ldsb[0][0] + tid * 16;

  auto stage = [&](int BOFF){
    gload16(kp,           sd + BOFF);
    gload16(kp + 32 * DK, sd + BOFF + 4096);
    gload16(vp,           sd + BOFF + 8192);
    gload16(vp + 32 * T,  sd + BOFF + 12288);
    kp += 64 * DK; vp += 64;
  };

  // persistent LDS frag addresses
  const char* ba[2][4];
  #pragma unroll
  for (int t2 = 0; t2 < 2; ++t2)
    #pragma unroll
    for (int kk = 0; kk < 4; ++kk)
      ba[t2][kk] = &ldsb[0][0] + (t2 * 32 + l31) * 128 + ((((kk << 1) | h5) ^ l7) << 4);

  // prologue: stage tiles 0,1; compute sc(0) from buf 0
  stage(0);
  stage(16384);
  __syncthreads();

  f16v scA0, scA1;
  {
    s8 kf0[4], kf1[4];
    #pragma unroll
    for (int kk = 0; kk < 4; ++kk){
      kf0[kk] = *(const s8*)(ba[0][kk]);
      kf1[kk] = *(const s8*)(ba[1][kk]);
    }
    #pragma unroll
    for (int i = 0; i < 16; ++i){ scA0[i] = 0.f; scA1[i] = 0.f; }
    #pragma unroll
    for (int kk = 0; kk < 4; ++kk) scA0 = MFMA32(kf0[kk], qf[kk], scA0);
    #pragma unroll
    for (int kk = 0; kk < 4; ++kk) scA1 = MFMA32(kf1[kk], qf[kk], scA1);
  }

  int curOff = 0, nxtOff = 16384, filOff = 32768;
  #pragma unroll 1
  for (int it = 0; it < 64; ++it){
    // stage tile it+2 into fil buffer
    if (it < 62) stage(filOff);

    // QK(t+1) from nxt buffer (overlaps softmax below on the other pipe)
    f16v scB0, scB1;
    if (it < 63){
      s8 kf0[4], kf1[4];
      #pragma unroll
      for (int kk = 0; kk < 4; ++kk){
        kf0[kk] = *(const s8*)(ba[0][kk] + nxtOff);
        kf1[kk] = *(const s8*)(ba[1][kk] + nxtOff);
      }
      #pragma unroll
      for (int i = 0; i < 16; ++i){ scB0[i] = 0.f; scB1[i] = 0.f; }
      __builtin_amdgcn_s_setprio(1);
      #pragma unroll
      for (int kk = 0; kk < 4; ++kk) scB0 = MFMA32(kf0[kk], qf[kk], scB0);
      #pragma unroll
      for (int kk = 0; kk < 4; ++kk) scB1 = MFMA32(kf1[kk], qf[kk], scB1);
      __builtin_amdgcn_s_setprio(0);
    }

    // softmax of tile it (scA from last iteration)
    float p0[16], p1[16];
    #pragma unroll
    for (int i = 0; i < 16; ++i){
      p0[i] = __builtin_amdgcn_exp2f(scA0[i]);
      p1[i] = __builtin_amdgcn_exp2f(scA1[i]);
    }
    float r0 = (p0[0]+p0[1]) + (p0[2]+p0[3]);
    float r1 = (p0[4]+p0[5]) + (p0[6]+p0[7]);
    float r2 = (p0[8]+p0[9]) + (p0[10]+p0[11]);
    float r3 = (p0[12]+p0[13]) + (p0[14]+p0[15]);
    float r4 = (p1[0]+p1[1]) + (p1[2]+p1[3]);
    float r5 = (p1[4]+p1[5]) + (p1[6]+p1[7]);
    float r6 = (p1[8]+p1[9]) + (p1[10]+p1[11]);
    float r7 = (p1[12]+p1[13]) + (p1[14]+p1[15]);
    ls += ((r0+r1)+(r2+r3)) + ((r4+r5)+(r6+r7));
    unsigned a0 = pk2(p0[0],p0[1]),  a1 = pk2(p0[2],p0[3]);
    unsigned a2 = pk2(p0[4],p0[5]),  a3 = pk2(p0[6],p0[7]);
    unsigned a4 = pk2(p0[8],p0[9]),  a5 = pk2(p0[10],p0[11]);
    unsigned a6 = pk2(p0[12],p0[13]), a7 = pk2(p0[14],p0[15]);
    unsigned b0 = pk2(p1[0],p1[1]),  b1 = pk2(p1[2],p1[3]);
    unsigned b2 = pk2(p1[4],p1[5]),  b3 = pk2(p1[6],p1[7]);
    unsigned b4 = pk2(p1[8],p1[9]),  b5 = pk2(p1[10],p1[11]);
    unsigned b6 = pk2(p1[12],p1[13]), b7 = pk2(p1[14],p1[15]);
    unsigned e0,o0, e1,o1, e2,o2, e3,o3, e4,o4, e5,o5, e6,o6, e7,o7;
    swp(a0, a2, e0, o0);  swp(a1, a3, e1, o1);   // kv 0-15
    swp(a4, a6, e2, o2);  swp(a5, a7, e3, o3);   // kv 16-31
    swp(b0, b2, e4, o4);  swp(b1, b3, e5, o5);   // kv 32-47
    swp(b4, b6, e6, o6);  swp(b5, b7, e7, o7);   // kv 48-63
    u32x4 pu0 = {e0, e1, o0, o1};
    u32x4 pu1 = {e2, e3, o2, o3};
    u32x4 pu2 = {e4, e5, o4, o5};
    u32x4 pu3 = {e6, e7, o6, o7};
    s8 pa0 = __builtin_bit_cast(s8, pu0);
    s8 pa1 = __builtin_bit_cast(s8, pu1);
    s8 pa2 = __builtin_bit_cast(s8, pu2);
    s8 pa3 = __builtin_bit_cast(s8, pu3);

    // V frags of tile it (cur buffer)
    s8 vf0[4], vf1[4];
    #pragma unroll
    for (int p = 0; p < 4; ++p){
      vf0[p] = *(const s8*)(ba[0][p] + curOff + 8192);
      vf1[p] = *(const s8*)(ba[1][p] + curOff + 8192);
    }
    // O^T += V^T · P
    __builtin_amdgcn_s_setprio(1);
    oa0 = MFMA32(vf0[0], pa0, oa0);
    oa0 = MFMA32(vf0[1], pa1, oa0);
    oa0 = MFMA32(vf0[2], pa2, oa0);
    oa0 = MFMA32(vf0[3], pa3, oa0);
    oa1 = MFMA32(vf1[0], pa0, oa1);
    oa1 = MFMA32(vf1[1], pa1, oa1);
    oa1 = MFMA32(vf1[2], pa2, oa1);
    oa1 = MFMA32(vf1[3], pa3, oa1);
    __builtin_amdgcn_s_setprio(0);

    // rotate pipeline state
    if (it < 63){ scA0 = scB0; scA1 = scB1; }
    int tmp = curOff; curOff = nxtOff; nxtOff = filOff; filOff = tmp;
    __syncthreads();
  }

  // epilogue: lane's outputs all share q = l31
  float lq = ls + __shfl_xor(ls, 32);
  float inv = 1.f / lq;
  const int t = Q0w + l31;
  unsigned short* crow = cat + (size_t)t * DM + h * DK;
  #pragma unroll
  for (int g = 0; g < 4; ++g){
    u32x2 w0, w1;
    w0[0] = pk2(oa0[g*4+0] * inv, oa0[g*4+1] * inv);
    w0[1] = pk2(oa0[g*4+2] * inv, oa0[g*4+3] * inv);
    w1[0] = pk2(oa1[g*4+0] * inv, oa1[g*4+1] * inv);
    w1[1] = pk2(oa1[g*4+2] * inv, oa1[g*4+3] * inv);
    *reinterpret_cast<u32x2*>(crow + g * 8 + h5 * 4)      = w0;
    *reinterpret_cast<u32x2*>(crow + 32 + g * 8 + h5 * 4) = w1;
  }
}

// ---------------------------------------------------------------------------
extern "C" void kernel_launch(void* const* d_in, const int* in_sizes, int n_in,
                              void* d_out, int out_size, void* d_ws, size_t ws_size,
                              hipStream_t stream){
  const float* X   = (const float*)d_in[0];
  const float* Wq  = (const float*)d_in[1];
  const float* bq  = (const float*)d_in[2];
  const float* Wk  = (const float*)d_in[3];
  const float* bk  = (const float*)d_in[4];
  const float* Wv  = (const float*)d_in[5];
  const float* bv  = (const float*)d_in[6];
  const float* Whq = (const float*)d_in[7];
  const float* bhq = (const float*)d_in[8];
  const float* Whk = (const float*)d_in[9];
  const float* bhk = (const float*)d_in[10];
  const float* Whv = (const float*)d_in[11];
  const float* bhv = (const float*)d_in[12];
  const float* Wo  = (const float*)d_in[13];
  const float* bo  = (const float*)d_in[14];

  char* w = (char*)d_ws;
  size_t off = 0;
  auto alloc = [&](size_t bytes) -> char* {
    char* p = w + off;
    off = (off + bytes + 255) & ~(size_t)255;
    return p;
  };
  unsigned short* Xbf = (unsigned short*)alloc((size_t)T * DM * 2);   // reused as cat
  unsigned short* Wob = (unsigned short*)alloc((size_t)DM * DM * 2);
  unsigned short* W3b = (unsigned short*)alloc((size_t)192 * DM * 2);
  unsigned short* Whb = (unsigned short*)alloc((size_t)48 * 64 * 64 * 2);
  float* beff = (float*)alloc(48 * 64 * 4);
  unsigned short* Yq  = (unsigned short*)alloc((size_t)T * 64 * 2);
  unsigned short* Yk  = (unsigned short*)alloc((size_t)T * 64 * 2);
  unsigned short* Yv  = (unsigned short*)alloc((size_t)T * 64 * 2);
  unsigned short* qhb = (unsigned short*)alloc((size_t)H * T * DK * 2);
  unsigned short* khb = (unsigned short*)alloc((size_t)H * T * DK * 2);
  unsigned short* vtb = (unsigned short*)alloc((size_t)H * T * DK * 2);
  unsigned short* cat = Xbf;   // alias: Xbf dead after gemm1

  cvt_bf16<<<(T * DM / 4) / 256, 256, 0, stream>>>(X, Xbf, T * DM / 4);
  {
    int total = N_WOB + 3 * N_W3 + 3 * N_WH + 3072;
    prep_all<<<(total + 255) / 256, 256, 0, stream>>>(
        Wo, Wq, Wk, Wv, Whq, Whk, Whv, bq, bk, bv, bhq, bhk, bhv,
        Wob, W3b, Whb, beff);
  }

  // stage 1: Y = X · W3^T (4096 x 192 x 1024), 64x64 tiles
  gemmX<4, 64, 64, 3><<<(T / 64) * 3, 256, 0, stream>>>(Xbf, W3b, nullptr, Yq, Yk, Yv, nullptr);

  // stage 2: per-head 64x64 linears
  gemm_heads<<<(T / 256) * 48, 256, 0, stream>>>(Yq, Yk, Yv, Whb, beff, qhb, khb, vtb);

  // attention (32x32 MFMA, cross-iteration pipeline)
  attn_fwd<<<(T / 128) * H, 256, 0, stream>>>(qhb, khb, vtb, cat);

  // final projection (f32 out)
  gemmX<2, 128, 64, 16><<<(T / 128) * 16, 256, 0, stream>>>(cat, Wob, bo, nullptr, nullptr, nullptr, (float*)d_out);
}